// Round 5
// baseline (415.681 us; speedup 1.0000x reference)
//
#include <hip/hip_runtime.h>
#include <math.h>

#define DM 1024
#define DF 1024
#define NE 8
#define NBIN 16          // (pass, expert) bins: bin = p*8 + e
#define MAXT 288         // max total worklist tiles (both passes)
#define BM 128
#define BN 128
#define NIT 32           // K iterations (BK=32)
#define WAITVM8 0xF78    // s_waitcnt vmcnt(8), expcnt=7, lgkmcnt=15 (no-wait)

typedef __bf16 bf16x8 __attribute__((ext_vector_type(8)));
typedef __bf16 bf16x4 __attribute__((ext_vector_type(4)));
typedef float floatx4 __attribute__((ext_vector_type(4)));

typedef const __attribute__((address_space(1))) unsigned int* gas_t;
typedef __attribute__((address_space(3))) unsigned int* las_t;

__device__ __forceinline__ void ld_lds16(const void* g, void* l) {
    __builtin_amdgcn_global_load_lds((gas_t)g, (las_t)l, 16, 0, 0);
}

// ---------------- ws layout ----------------
// [0, 33.5M)      Xb   bf16[T][1024]
// [33.5M, 50.3M)  WeT  bf16[8][1024][1024]  ([e][n][k])
// [50.3M, ...)    routing: ntiles, wl (int4[MAXT]), blk_cnt, blk_base, tok_e, tok_w,
//                 gath_tok, gath_w

__global__ void convert_weT(const float* __restrict__ We, __bf16* __restrict__ WeT) {
    int n  = blockIdx.x * 256 + threadIdx.x;
    int kc = blockIdx.y * 8;
    int e  = blockIdx.z;
    const float* src = We + ((size_t)e << 20) + (size_t)kc * DF + n;
    bf16x8 v;
#pragma unroll
    for (int j = 0; j < 8; ++j) v[j] = (__bf16)src[(size_t)j * DF];
    *(bf16x8*)&WeT[((size_t)e << 20) + (size_t)n * DM + kc] = v;
}

// fused: gate logits + top-2 + sigmoid + X -> bf16 conversion
__global__ void gate_kernel(const float4* __restrict__ X4, const float4* __restrict__ Wg4,
                            const float* __restrict__ bg, int* __restrict__ tok_e,
                            float* __restrict__ tok_w, __bf16* __restrict__ Xb, int T) {
    int wid  = threadIdx.x >> 6;
    int lane = threadIdx.x & 63;
    int t = blockIdx.x * 4 + wid;
    if (t >= T) return;
    float acc[NE] = {};
    float4 xs[4];
#pragma unroll
    for (int c = 0; c < 4; ++c) {
        float4 xv = X4[(size_t)t * 256 + c * 64 + lane];
        xs[c] = xv;
#pragma unroll
        for (int e = 0; e < NE; ++e) {
            float4 wv = Wg4[e * 256 + c * 64 + lane];
            acc[e] += xv.x * wv.x + xv.y * wv.y + xv.z * wv.z + xv.w * wv.w;
        }
    }
#pragma unroll
    for (int c = 0; c < 4; ++c) {
        bf16x4 v;
        v[0] = (__bf16)xs[c].x; v[1] = (__bf16)xs[c].y;
        v[2] = (__bf16)xs[c].z; v[3] = (__bf16)xs[c].w;
        *(bf16x4*)&Xb[(size_t)t * DM + c * 256 + lane * 4] = v;
    }
#pragma unroll
    for (int e = 0; e < NE; ++e) {
#pragma unroll
        for (int off = 32; off > 0; off >>= 1)
            acc[e] += __shfl_down(acc[e], off, 64);
    }
    if (lane == 0) {
        float l[NE];
#pragma unroll
        for (int e = 0; e < NE; ++e) l[e] = acc[e] + bg[e];
        int b0 = 0; float v0 = l[0];
        for (int e = 1; e < NE; ++e) if (l[e] > v0) { v0 = l[e]; b0 = e; }
        int b1 = -1; float v1 = -3.4e38f;
        for (int e = 0; e < NE; ++e) if (e != b0 && l[e] > v1) { v1 = l[e]; b1 = e; }
        tok_e[2 * t]     = b0;  tok_e[2 * t + 1] = b1;
        tok_w[2 * t]     = 1.f / (1.f + expf(-v0));
        tok_w[2 * t + 1] = 1.f / (1.f + expf(-v1));
    }
}

__global__ void hist_kernel(const int* __restrict__ tok_e, int* __restrict__ blk_cnt, int n) {
    int b = blockIdx.x, tid = threadIdx.x;
    int idx  = b * 256 + tid;
    int lane = tid & 63, w = tid >> 6;
    int bin = (idx < n) ? ((idx & 1) * NE + tok_e[idx]) : -1;
    __shared__ int wc[4][NBIN];
#pragma unroll
    for (int bx = 0; bx < NBIN; ++bx) {
        unsigned long long m = __ballot(bin == bx);
        if (lane == 0) wc[w][bx] = (int)__popcll(m);
    }
    __syncthreads();
    if (tid < NBIN) blk_cnt[b * NBIN + tid] = wc[0][tid] + wc[1][tid] + wc[2][tid] + wc[3][tid];
}

// scan + build a single merged worklist covering all 16 (pass,expert) bins
__global__ void scan_kernel(const int* __restrict__ blk_cnt, int* __restrict__ blk_base,
                            int4* __restrict__ wl, int* __restrict__ ntiles, int NB) {
    __shared__ int c[2048];
    __shared__ int tot[NBIN], base[NBIN];
    int tid = threadIdx.x;
    for (int i = tid; i < NB * NBIN; i += 256) c[i] = blk_cnt[i];
    __syncthreads();
    if (tid < NBIN) {
        int s = 0;
        for (int b = 0; b < NB; ++b) s += c[b * NBIN + tid];
        tot[tid] = s;
    }
    __syncthreads();
    if (tid == 0) {
        int s = 0;
        for (int b = 0; b < NBIN; ++b) { base[b] = s; s += tot[b]; }
    }
    __syncthreads();
    if (tid < NBIN) {
        int run = base[tid];
        for (int b = 0; b < NB; ++b) { int v = c[b * NBIN + tid]; c[b * NBIN + tid] = run; run += v; }
    }
    __syncthreads();
    for (int i = tid; i < NB * NBIN; i += 256) blk_base[i] = c[i];
    if (tid == 0) {
        int nt = 0;
        for (int bin = 0; bin < NBIN; ++bin) {
            int cnt = tot[bin], sg = base[bin];
            for (int r0 = 0; r0 < cnt; r0 += BM)
                wl[nt++] = make_int4(bin & 7, r0, sg, cnt);
        }
        ntiles[0] = nt;
    }
}

__global__ void scatter_kernel(const int* __restrict__ tok_e, const float* __restrict__ tok_w,
                               const int* __restrict__ blk_base, int* __restrict__ gath_tok,
                               float* __restrict__ gath_w, int n) {
    int b = blockIdx.x, tid = threadIdx.x;
    int idx  = b * 256 + tid;
    int lane = tid & 63, w = tid >> 6;
    bool act = idx < n;
    int bin = act ? ((idx & 1) * NE + tok_e[idx]) : -1;
    __shared__ int wc[4][NBIN], wb[4][NBIN];
    int myrank = 0;
#pragma unroll
    for (int bx = 0; bx < NBIN; ++bx) {
        unsigned long long m = __ballot(bin == bx);
        if (lane == 0) wc[w][bx] = (int)__popcll(m);
        if (bin == bx) myrank = (int)__popcll(m & ((1ull << lane) - 1ull));
    }
    __syncthreads();
    if (tid < NBIN) {
        int run = blk_base[b * NBIN + tid];
#pragma unroll
        for (int wv = 0; wv < 4; ++wv) { wb[wv][tid] = run; run += wc[wv][tid]; }
    }
    __syncthreads();
    if (act) {
        int pos = wb[w][bin] + myrank;
        gath_tok[pos] = idx >> 1;
        gath_w[pos]   = tok_w[idx];
    }
}

// Quad-buffered, depth-2 pipelined grouped GEMM.
// LDS layout per buffer (A and B alike): 8 groups of 16 rows; row r, k-chunk kc(0..3)
// stored at group (r>>4), lane (r&15)*4 + (kc ^ (((r&15)>>1)&3)), 16B per lane.
__global__ __launch_bounds__(256) void expert_gemm_mfma(
        const __bf16* __restrict__ Xb, const __bf16* __restrict__ WeT,
        const float* __restrict__ be, const int4* __restrict__ wl,
        const int* __restrict__ ntiles, const int* __restrict__ gtok,
        const float* __restrict__ gw, float* __restrict__ out) {
    if ((int)blockIdx.x >= ntiles[0]) return;
    int4 ent = wl[blockIdx.x];
    int e = ent.x, row0 = ent.y, seg = ent.z, n_e = ent.w;
    int col0 = blockIdx.y * BN;

    __shared__ __align__(16) __bf16 As[4 * BM * 32];   // 32 KB (4 buffers x 8 KB)
    __shared__ __align__(16) __bf16 Bs[4 * BN * 32];   // 32 KB
    __shared__ int   s_tok[BM];
    __shared__ float s_w[BM];

    int tid = threadIdx.x;
    if (tid < BM) {
        int gr = row0 + tid;
        s_tok[tid] = (gr < n_e) ? gtok[seg + gr] : gtok[seg];
        s_w[tid]   = (gr < n_e) ? gw[seg + gr]   : 0.f;
    }
    __syncthreads();

    int lane = tid & 63, w = tid >> 6;
    int lr = lane >> 2;                 // row-within-16
    int lc = lane & 3;                  // chunk slot
    int kc = lc ^ ((lr >> 1) & 3);      // XOR-swizzled k-chunk (0..3), 8 elems each

    const __bf16* aptr[2];
    const __bf16* bptr[2];
#pragma unroll
    for (int p = 0; p < 2; ++p) {
        int r = p * 64 + w * 16 + lr;
        aptr[p] = Xb + (size_t)s_tok[r] * DM + kc * 8;
        bptr[p] = WeT + ((size_t)e << 20) + (size_t)(col0 + r) * DM + kc * 8;
    }

    // stage k-tile kk into buffer buf: 4 x global_load_lds (16B/lane, lane-linear dst)
#define STAGE(kk, buf)                                                         \
    {                                                                          \
        int _ko = (kk) * 32;                                                   \
        int _b  = (buf) * (BM * 32);                                           \
        ld_lds16(aptr[0] + _ko, &As[_b + (0 * 4 + w) * 512]);                  \
        ld_lds16(aptr[1] + _ko, &As[_b + (1 * 4 + w) * 512]);                  \
        ld_lds16(bptr[0] + _ko, &Bs[_b + (0 * 4 + w) * 512]);                  \
        ld_lds16(bptr[1] + _ko, &Bs[_b + (1 * 4 + w) * 512]);                  \
    }

    STAGE(0, 0);
    STAGE(1, 1);

    int wr = (w >> 1) * 64, wcc = (w & 1) * 64;
    int m16 = lane & 15, q = lane >> 4;
    int qsw = (q ^ ((m16 >> 1) & 3)) * 8;       // de-swizzled chunk offset (elems)
    int wr4 = wr >> 4, wc4 = wcc >> 4;

    floatx4 acc[4][4] = {};

    for (int k = 0; k < NIT; ++k) {
        int k2 = (k + 2 < NIT) ? k + 2 : 0;     // dummy re-stage at tail (never read)
        STAGE(k2, (k + 2) & 3);
        __builtin_amdgcn_s_waitcnt(WAITVM8);    // drain tile k only; k+1,k+2 in flight
        __builtin_amdgcn_s_barrier();
        int ab = (k & 3) * (BM * 32);
        bf16x8 af[4], bfr[4];
#pragma unroll
        for (int i = 0; i < 4; ++i)
            af[i] = *(const bf16x8*)&As[ab + (wr4 + i) * 512 + m16 * 32 + qsw];
#pragma unroll
        for (int i = 0; i < 4; ++i)
            bfr[i] = *(const bf16x8*)&Bs[ab + (wc4 + i) * 512 + m16 * 32 + qsw];
#pragma unroll
        for (int i = 0; i < 4; ++i)
#pragma unroll
            for (int j = 0; j < 4; ++j)
                acc[i][j] = __builtin_amdgcn_mfma_f32_16x16x32_bf16(af[i], bfr[j], acc[i][j], 0, 0, 0);
    }
#undef STAGE

    // epilogue: out[t][c] += w * (acc + be[c]); C/D: col=lane&15, row=q*4+reg
#pragma unroll
    for (int j = 0; j < 4; ++j) {
        int c = col0 + wcc + j * 16 + m16;
        float bias = be[e * DF + c];
#pragma unroll
        for (int i = 0; i < 4; ++i) {
#pragma unroll
            for (int rg = 0; rg < 4; ++rg) {
                int rl = wr + i * 16 + q * 4 + rg;
                int gr = row0 + rl;
                if (gr < n_e)
                    atomicAdd(&out[(size_t)s_tok[rl] * DF + c], s_w[rl] * (acc[i][j][rg] + bias));
            }
        }
    }
}

extern "C" void kernel_launch(void* const* d_in, const int* in_sizes, int n_in,
                              void* d_out, int out_size, void* d_ws, size_t ws_size,
                              hipStream_t stream) {
    const float* x  = (const float*)d_in[0];
    const float* Wg = (const float*)d_in[1];
    const float* bg = (const float*)d_in[2];
    const float* We = (const float*)d_in[3];
    const float* be = (const float*)d_in[4];
    float* out = (float*)d_out;

    int T = in_sizes[0] / DM;
    int n_slots = 2 * T;
    int NB = (n_slots + 255) / 256;

    char* ws = (char*)d_ws;
    size_t xb_bytes  = (size_t)T * DM * 2;
    size_t weT_bytes = (size_t)NE * DM * DF * 2;
    __bf16* Xb  = (__bf16*)ws;
    __bf16* WeT = (__bf16*)(ws + xb_bytes);
    char* rt = ws + xb_bytes + weT_bytes;
    int*   ntiles    = (int*)(rt + 0);
    int4*  wl        = (int4*)(rt + 64);
    int*   blk_cnt   = (int*)(rt + 64 + MAXT * 16);
    int*   blk_base  = (int*)((char*)blk_cnt + (size_t)NB * NBIN * 4);
    int*   tok_e     = (int*)((char*)blk_base + (size_t)NB * NBIN * 4);
    float* tok_w     = (float*)((char*)tok_e + (size_t)n_slots * 4);
    int*   gath_tok  = (int*)((char*)tok_w + (size_t)n_slots * 4);
    float* gath_w    = (float*)((char*)gath_tok + (size_t)n_slots * 4);

    hipMemsetAsync(d_out, 0, (size_t)out_size * sizeof(float), stream);

    convert_weT<<<dim3(DF / 256, DM / 8, NE), 256, 0, stream>>>(We, WeT);
    gate_kernel<<<(T + 3) / 4, 256, 0, stream>>>((const float4*)x, (const float4*)Wg,
                                                 bg, tok_e, tok_w, Xb, T);
    hist_kernel<<<NB, 256, 0, stream>>>(tok_e, blk_cnt, n_slots);
    scan_kernel<<<1, 256, 0, stream>>>(blk_cnt, blk_base, wl, ntiles, NB);
    scatter_kernel<<<NB, 256, 0, stream>>>(tok_e, tok_w, blk_base, gath_tok, gath_w, n_slots);

    dim3 grid(MAXT, DF / BN);
    expert_gemm_mfma<<<grid, 256, 0, stream>>>(Xb, WeT, be, wl, ntiles,
                                               gath_tok, gath_w, out);
}